// Round 8
// baseline (215.851 us; speedup 1.0000x reference)
//
#include <hip/hip_runtime.h>

// Problem constants: B=8, N=7, C=64, H=128, W=128
#define NB     8
#define NN     7
#define D_EL   (64*128*128)       // 1048576 floats per (b,n)
#define DV     (D_EL/4)           // 262144 float4 per (b,n)
#define NPAIR  28                 // unique (i<=j) pairs of 7
#define THREADS 256

// shared chunking for gram + apply: one block per (b, chunk);
// chunk = 256 float4 per stream (4KB burst per stream)
#define ACH    256                // float4 per chunk per stream
#define ACPB   (DV/ACH)           // 1024 chunks per batch

__device__ __forceinline__ int pair_idx(int i, int j) {
    return i * 7 - (i * (i - 1)) / 2 + (j - i);
}

// ---------------------------------------------------------------------------
// Kernel 1: phase-separated LDS-staged Gram partials (R7-apply structure).
//   Phase 1: burst the 7 x2 sub-streams (4KB each) into LDS.
//   Phase 2: per-thread 28 pair products from LDS, then block reduce.
// Replaces the 7-way interleaved 1MB-strided read (measured ~4 TB/s) with
// back-to-back 4KB bursts (apply's phased pattern measured ~5.2 TB/s).
// ---------------------------------------------------------------------------
__global__ __launch_bounds__(THREADS)
void gram_partial(const float* __restrict__ x2, float* __restrict__ partials) {
    const int b     = blockIdx.x / ACPB;
    const int chunk = blockIdx.x % ACPB;
    const int p0    = chunk * ACH;

    __shared__ float4 x2s[NN * ACH];     // 28 KB
    const float4* v2 = (const float4*)(x2 + (size_t)b * NN * D_EL);

#pragma unroll
    for (int m = 0; m < NN; ++m)
        x2s[m * ACH + threadIdx.x] = v2[(size_t)m * DV + p0 + threadIdx.x];
    __syncthreads();

    float4 w[NN];
#pragma unroll
    for (int m = 0; m < NN; ++m) w[m] = x2s[m * ACH + threadIdx.x];

    float acc[NPAIR];
    int k = 0;
#pragma unroll
    for (int i = 0; i < NN; ++i)
#pragma unroll
        for (int j = i; j < NN; ++j, ++k) {
            acc[k] = w[i].x * w[j].x;
            acc[k] = fmaf(w[i].y, w[j].y, acc[k]);
            acc[k] = fmaf(w[i].z, w[j].z, acc[k]);
            acc[k] = fmaf(w[i].w, w[j].w, acc[k]);
        }

    __shared__ float lds[4][NPAIR];
    const int lane = threadIdx.x & 63;
    const int wid  = threadIdx.x >> 6;
#pragma unroll
    for (int q = 0; q < NPAIR; ++q) {
        float s = acc[q];
#pragma unroll
        for (int o = 32; o > 0; o >>= 1) s += __shfl_down(s, o, 64);
        if (lane == 0) lds[wid][q] = s;
    }
    __syncthreads();
    if (threadIdx.x < NPAIR) {
        float s = lds[0][threadIdx.x] + lds[1][threadIdx.x]
                + lds[2][threadIdx.x] + lds[3][threadIdx.x];
        partials[(size_t)blockIdx.x * NPAIR + threadIdx.x] = s;
    }
}

// ---------------------------------------------------------------------------
// Kernel 2: reduce 1024 partial-sets/batch -> energy (7x7) -> attention.
// softmax(rowmax(E)-E) == softmax(-E) (shift-invariant).
// ---------------------------------------------------------------------------
__global__ __launch_bounds__(THREADS)
void softmax_k(const float* __restrict__ partials, float* __restrict__ att) {
    const int b = blockIdx.x;
    const float* pb = partials + (size_t)b * ACPB * NPAIR;

    float acc[NPAIR];
#pragma unroll
    for (int k = 0; k < NPAIR; ++k) acc[k] = 0.f;
    for (int s = threadIdx.x; s < ACPB; s += THREADS) {
#pragma unroll
        for (int k = 0; k < NPAIR; ++k) acc[k] += pb[(size_t)s * NPAIR + k];
    }

    __shared__ float lds[4][NPAIR];
    __shared__ float e_s[NPAIR];
    const int lane = threadIdx.x & 63;
    const int wid  = threadIdx.x >> 6;
#pragma unroll
    for (int k = 0; k < NPAIR; ++k) {
        float s = acc[k];
#pragma unroll
        for (int o = 32; o > 0; o >>= 1) s += __shfl_down(s, o, 64);
        if (lane == 0) lds[wid][k] = s;
    }
    __syncthreads();
    if (threadIdx.x < NPAIR) {
        e_s[threadIdx.x] = lds[0][threadIdx.x] + lds[1][threadIdx.x]
                         + lds[2][threadIdx.x] + lds[3][threadIdx.x];
    }
    __syncthreads();

    if (threadIdx.x < NN) {
        const int n = threadIdx.x;
        float z[NN];
#pragma unroll
        for (int m = 0; m < NN; ++m) {
            const int i = n < m ? n : m;
            const int j = n < m ? m : n;
            z[m] = -e_s[pair_idx(i, j)];
        }
        float mx = z[0];
#pragma unroll
        for (int m = 1; m < NN; ++m) mx = fmaxf(mx, z[m]);
        float p[NN], s = 0.f;
#pragma unroll
        for (int m = 0; m < NN; ++m) { p[m] = expf(z[m] - mx); s += p[m]; }
        const float inv = 1.f / s;
#pragma unroll
        for (int m = 0; m < NN; ++m)
            att[(size_t)b * NN * NN + n * NN + m] = p[m] * inv;
    }
}

// ---------------------------------------------------------------------------
// Kernel 3: phase-separated LDS-staged apply (R7-exact, best measured:
// 133us, 5.2 TB/s fabric).
//   Phase 1: burst the 7 x2 sub-streams (L3-served) into LDS.
//   Phase 2: 7 clean copy-like (x1 read -> out write) stream pairs.
// ---------------------------------------------------------------------------
__global__ __launch_bounds__(THREADS)
void apply_k(const float* __restrict__ x1, const float* __restrict__ x2,
             const float* __restrict__ att, const float* __restrict__ gamma,
             float* __restrict__ out) {
    const int b     = blockIdx.x / ACPB;
    const int chunk = blockIdx.x % ACPB;
    const int p0    = chunk * ACH;

    __shared__ float4 x2s[NN * ACH];     // 28 KB
    __shared__ float  a_s[NN * NN];

    if (threadIdx.x < NN * NN)
        a_s[threadIdx.x] = att[(size_t)b * NN * NN + threadIdx.x];

    const float4* v2 = (const float4*)(x2 + (size_t)b * NN * D_EL);
#pragma unroll
    for (int m = 0; m < NN; ++m)
        x2s[m * ACH + threadIdx.x] = v2[(size_t)m * DV + p0 + threadIdx.x];
    __syncthreads();

    float4 v[NN];
#pragma unroll
    for (int m = 0; m < NN; ++m) v[m] = x2s[m * ACH + threadIdx.x];

    const float g = gamma[0];
    const float4* v1 = (const float4*)(x1 + (size_t)b * NN * D_EL);
    float4*       vo = (float4*)((float*)out + (size_t)b * NN * D_EL);
    const int p = p0 + threadIdx.x;

#pragma unroll
    for (int n = 0; n < NN; ++n) {
        const float4 x = v1[(size_t)n * DV + p];
        float ox = 0.f, oy = 0.f, oz = 0.f, ow = 0.f;
#pragma unroll
        for (int m = 0; m < NN; ++m) {
            const float a = a_s[n * NN + m];
            ox = fmaf(a, v[m].x, ox);
            oy = fmaf(a, v[m].y, oy);
            oz = fmaf(a, v[m].z, oz);
            ow = fmaf(a, v[m].w, ow);
        }
        float4 r;
        r.x = fmaf(x.x, g * ox, x.x);
        r.y = fmaf(x.y, g * oy, x.y);
        r.z = fmaf(x.z, g * oz, x.z);
        r.w = fmaf(x.w, g * ow, x.w);
        vo[(size_t)n * DV + p] = r;
    }
}

extern "C" void kernel_launch(void* const* d_in, const int* in_sizes, int n_in,
                              void* d_out, int out_size, void* d_ws, size_t ws_size,
                              hipStream_t stream) {
    const float* x1    = (const float*)d_in[0];
    const float* x2    = (const float*)d_in[1];
    const float* gamma = (const float*)d_in[2];
    float*       out   = (float*)d_out;

    float* partials = (float*)d_ws;                          // NB*ACPB*NPAIR floats (~0.92 MB)
    float* att      = partials + (size_t)NB * ACPB * NPAIR;  // NB*49 floats

    gram_partial<<<dim3(NB * ACPB), dim3(THREADS), 0, stream>>>(x2, partials);
    softmax_k  <<<dim3(NB),         dim3(THREADS), 0, stream>>>(partials, att);
    apply_k    <<<dim3(NB * ACPB),  dim3(THREADS), 0, stream>>>(x1, x2, att, gamma, out);
}

// Round 9
// 205.054 us; speedup vs baseline: 1.0527x; 1.0527x over previous
//
#include <hip/hip_runtime.h>

// Problem constants: B=8, N=7, C=64, H=128, W=128
#define NB     8
#define NN     7
#define D_EL   (64*128*128)       // 1048576 floats per (b,n)
#define DV     (D_EL/4)           // 262144 float4 per (b,n)
#define NPAIR  28                 // unique (i<=j) pairs of 7
#define THREADS 256

// gram: fat blocks, phased burst loads
#define GCH     256               // float4 per stream per phase (4KB burst)
#define GPHASES 4                 // phases per block -> 16KB/stream/block
#define GCPB    (DV/(GCH*GPHASES))// 256 blocks per batch

// apply: one block per (b, chunk); chunk = 256 float4 per stream
#define ACH    256
#define ACPB   (DV/ACH)           // 1024 chunks per batch

__device__ __forceinline__ int pair_idx(int i, int j) {
    return i * 7 - (i * (i - 1)) / 2 + (j - i);
}

// ---------------------------------------------------------------------------
// Kernel 1: Gram partials — fat blocks (R6) + phased burst loads (R7/R8).
//   4 x { burst 7x4KB into LDS, barrier, 28 pair-FMAs from LDS into regs }
//   then ONE block reduction.  Amortizes reduce/barrier cost over 112KB.
// ---------------------------------------------------------------------------
__global__ __launch_bounds__(THREADS)
void gram_partial(const float* __restrict__ x2, float* __restrict__ partials) {
    const int b   = blockIdx.x / GCPB;
    const int blk = blockIdx.x % GCPB;
    const float4* v2 = (const float4*)(x2 + (size_t)b * NN * D_EL);
    const int base0 = blk * (GCH * GPHASES);

    __shared__ float4 x2s[NN * GCH];     // 28 KB
    float acc[NPAIR];
#pragma unroll
    for (int k = 0; k < NPAIR; ++k) acc[k] = 0.f;

    for (int it = 0; it < GPHASES; ++it) {
        const int p0 = base0 + it * GCH;
        __syncthreads();                 // protect LDS from previous phase
#pragma unroll
        for (int m = 0; m < NN; ++m)
            x2s[m * GCH + threadIdx.x] = v2[(size_t)m * DV + p0 + threadIdx.x];
        __syncthreads();

        float4 w[NN];
#pragma unroll
        for (int m = 0; m < NN; ++m) w[m] = x2s[m * GCH + threadIdx.x];
        int k = 0;
#pragma unroll
        for (int i = 0; i < NN; ++i)
#pragma unroll
            for (int j = i; j < NN; ++j, ++k) {
                acc[k] = fmaf(w[i].x, w[j].x, acc[k]);
                acc[k] = fmaf(w[i].y, w[j].y, acc[k]);
                acc[k] = fmaf(w[i].z, w[j].z, acc[k]);
                acc[k] = fmaf(w[i].w, w[j].w, acc[k]);
            }
    }

    __shared__ float lds[4][NPAIR];
    const int lane = threadIdx.x & 63;
    const int wid  = threadIdx.x >> 6;
#pragma unroll
    for (int q = 0; q < NPAIR; ++q) {
        float s = acc[q];
#pragma unroll
        for (int o = 32; o > 0; o >>= 1) s += __shfl_down(s, o, 64);
        if (lane == 0) lds[wid][q] = s;
    }
    __syncthreads();
    if (threadIdx.x < NPAIR) {
        float s = lds[0][threadIdx.x] + lds[1][threadIdx.x]
                + lds[2][threadIdx.x] + lds[3][threadIdx.x];
        partials[(size_t)blockIdx.x * NPAIR + threadIdx.x] = s;
    }
}

// ---------------------------------------------------------------------------
// Kernel 2: reduce GCPB partial-sets/batch -> energy (7x7) -> attention.
// softmax(rowmax(E)-E) == softmax(-E) (shift-invariant).
// ---------------------------------------------------------------------------
__global__ __launch_bounds__(THREADS)
void softmax_k(const float* __restrict__ partials, float* __restrict__ att) {
    const int b = blockIdx.x;
    const float* pb = partials + (size_t)b * GCPB * NPAIR;

    float acc[NPAIR];
#pragma unroll
    for (int k = 0; k < NPAIR; ++k) acc[k] = 0.f;
    for (int s = threadIdx.x; s < GCPB; s += THREADS) {
#pragma unroll
        for (int k = 0; k < NPAIR; ++k) acc[k] += pb[(size_t)s * NPAIR + k];
    }

    __shared__ float lds[4][NPAIR];
    __shared__ float e_s[NPAIR];
    const int lane = threadIdx.x & 63;
    const int wid  = threadIdx.x >> 6;
#pragma unroll
    for (int k = 0; k < NPAIR; ++k) {
        float s = acc[k];
#pragma unroll
        for (int o = 32; o > 0; o >>= 1) s += __shfl_down(s, o, 64);
        if (lane == 0) lds[wid][k] = s;
    }
    __syncthreads();
    if (threadIdx.x < NPAIR) {
        e_s[threadIdx.x] = lds[0][threadIdx.x] + lds[1][threadIdx.x]
                         + lds[2][threadIdx.x] + lds[3][threadIdx.x];
    }
    __syncthreads();

    if (threadIdx.x < NN) {
        const int n = threadIdx.x;
        float z[NN];
#pragma unroll
        for (int m = 0; m < NN; ++m) {
            const int i = n < m ? n : m;
            const int j = n < m ? m : n;
            z[m] = -e_s[pair_idx(i, j)];
        }
        float mx = z[0];
#pragma unroll
        for (int m = 1; m < NN; ++m) mx = fmaxf(mx, z[m]);
        float p[NN], s = 0.f;
#pragma unroll
        for (int m = 0; m < NN; ++m) { p[m] = expf(z[m] - mx); s += p[m]; }
        const float inv = 1.f / s;
#pragma unroll
        for (int m = 0; m < NN; ++m)
            att[(size_t)b * NN * NN + n * NN + m] = p[m] * inv;
    }
}

// ---------------------------------------------------------------------------
// Kernel 3: phase-separated LDS-staged apply (R7-exact, best measured:
// 133us, 5.2 TB/s fabric).  DO NOT TOUCH.
// ---------------------------------------------------------------------------
__global__ __launch_bounds__(THREADS)
void apply_k(const float* __restrict__ x1, const float* __restrict__ x2,
             const float* __restrict__ att, const float* __restrict__ gamma,
             float* __restrict__ out) {
    const int b     = blockIdx.x / ACPB;
    const int chunk = blockIdx.x % ACPB;
    const int p0    = chunk * ACH;

    __shared__ float4 x2s[NN * ACH];     // 28 KB
    __shared__ float  a_s[NN * NN];

    if (threadIdx.x < NN * NN)
        a_s[threadIdx.x] = att[(size_t)b * NN * NN + threadIdx.x];

    const float4* v2 = (const float4*)(x2 + (size_t)b * NN * D_EL);
#pragma unroll
    for (int m = 0; m < NN; ++m)
        x2s[m * ACH + threadIdx.x] = v2[(size_t)m * DV + p0 + threadIdx.x];
    __syncthreads();

    float4 v[NN];
#pragma unroll
    for (int m = 0; m < NN; ++m) v[m] = x2s[m * ACH + threadIdx.x];

    const float g = gamma[0];
    const float4* v1 = (const float4*)(x1 + (size_t)b * NN * D_EL);
    float4*       vo = (float4*)((float*)out + (size_t)b * NN * D_EL);
    const int p = p0 + threadIdx.x;

#pragma unroll
    for (int n = 0; n < NN; ++n) {
        const float4 x = v1[(size_t)n * DV + p];
        float ox = 0.f, oy = 0.f, oz = 0.f, ow = 0.f;
#pragma unroll
        for (int m = 0; m < NN; ++m) {
            const float a = a_s[n * NN + m];
            ox = fmaf(a, v[m].x, ox);
            oy = fmaf(a, v[m].y, oy);
            oz = fmaf(a, v[m].z, oz);
            ow = fmaf(a, v[m].w, ow);
        }
        float4 r;
        r.x = fmaf(x.x, g * ox, x.x);
        r.y = fmaf(x.y, g * oy, x.y);
        r.z = fmaf(x.z, g * oz, x.z);
        r.w = fmaf(x.w, g * ow, x.w);
        vo[(size_t)n * DV + p] = r;
    }
}

extern "C" void kernel_launch(void* const* d_in, const int* in_sizes, int n_in,
                              void* d_out, int out_size, void* d_ws, size_t ws_size,
                              hipStream_t stream) {
    const float* x1    = (const float*)d_in[0];
    const float* x2    = (const float*)d_in[1];
    const float* gamma = (const float*)d_in[2];
    float*       out   = (float*)d_out;

    float* partials = (float*)d_ws;                          // NB*GCPB*NPAIR floats
    float* att      = partials + (size_t)NB * GCPB * NPAIR;  // NB*49 floats

    gram_partial<<<dim3(NB * GCPB), dim3(THREADS), 0, stream>>>(x2, partials);
    softmax_k  <<<dim3(NB),         dim3(THREADS), 0, stream>>>(partials, att);
    apply_k    <<<dim3(NB * ACPB),  dim3(THREADS), 0, stream>>>(x1, x2, att, gamma, out);
}

// Round 10
// 198.179 us; speedup vs baseline: 1.0892x; 1.0347x over previous
//
#include <hip/hip_runtime.h>

// Problem constants: B=8, N=7, C=64, H=128, W=128
#define NB     8
#define NN     7
#define D_EL   (64*128*128)       // 1048576 floats per (b,n)
#define DV     (D_EL/4)           // 262144 float4 per (b,n)
#define NPAIR  28                 // unique (i<=j) pairs of 7
#define BPB    256                // blocks per batch (gram)
#define CHUNKV (DV/BPB)           // 1024 float4 per gram block per stream (16KB)
#define ITERS  (CHUNKV/256)
#define THREADS 256

// apply: one block per (b, chunk); chunk = 256 float4 per stream (4KB)
#define ACH    256
#define ACPB   (DV/ACH)           // 1024 chunks per batch

__device__ __forceinline__ int pair_idx(int i, int j) {
    return i * 7 - (i * (i - 1)) / 2 + (j - i);
}

// ---------------------------------------------------------------------------
// Kernel 1: per-block partial Gram sums (R6/R7-exact; all structural
// variants measured ~60us -> structure-insensitive, leave alone).
// ---------------------------------------------------------------------------
__global__ __launch_bounds__(THREADS)
void gram_partial(const float* __restrict__ x2, float* __restrict__ partials) {
    const int b   = blockIdx.x / BPB;
    const int blk = blockIdx.x % BPB;
    const float4* base = (const float4*)(x2 + (size_t)b * NN * D_EL);
    const int p0 = blk * CHUNKV;

    float acc[NPAIR];
#pragma unroll
    for (int k = 0; k < NPAIR; ++k) acc[k] = 0.f;

#pragma unroll
    for (int it = 0; it < ITERS; ++it) {
        const int p = p0 + it * THREADS + threadIdx.x;
        float4 v[NN];
#pragma unroll
        for (int n = 0; n < NN; ++n) v[n] = base[(size_t)n * DV + p];
        int k = 0;
#pragma unroll
        for (int i = 0; i < NN; ++i)
#pragma unroll
            for (int j = i; j < NN; ++j, ++k) {
                acc[k] = fmaf(v[i].x, v[j].x, acc[k]);
                acc[k] = fmaf(v[i].y, v[j].y, acc[k]);
                acc[k] = fmaf(v[i].z, v[j].z, acc[k]);
                acc[k] = fmaf(v[i].w, v[j].w, acc[k]);
            }
    }

    __shared__ float lds[4][NPAIR];
    const int lane = threadIdx.x & 63;
    const int wid  = threadIdx.x >> 6;
#pragma unroll
    for (int k = 0; k < NPAIR; ++k) {
        float s = acc[k];
#pragma unroll
        for (int o = 32; o > 0; o >>= 1) s += __shfl_down(s, o, 64);
        if (lane == 0) lds[wid][k] = s;
    }
    __syncthreads();
    if (threadIdx.x < NPAIR) {
        float s = lds[0][threadIdx.x] + lds[1][threadIdx.x]
                + lds[2][threadIdx.x] + lds[3][threadIdx.x];
        partials[(size_t)blockIdx.x * NPAIR + threadIdx.x] = s;
    }
}

// ---------------------------------------------------------------------------
// Kernel 2: reduce partials -> energy (7x7) -> attention.
// softmax(rowmax(E)-E) == softmax(-E) (shift-invariant).
// ---------------------------------------------------------------------------
__global__ __launch_bounds__(THREADS)
void softmax_k(const float* __restrict__ partials, float* __restrict__ att) {
    const int b = blockIdx.x;
    const float* pb = partials + (size_t)b * BPB * NPAIR;

    float acc[NPAIR];
#pragma unroll
    for (int k = 0; k < NPAIR; ++k) acc[k] = pb[(size_t)threadIdx.x * NPAIR + k];

    __shared__ float lds[4][NPAIR];
    __shared__ float e_s[NPAIR];
    const int lane = threadIdx.x & 63;
    const int wid  = threadIdx.x >> 6;
#pragma unroll
    for (int k = 0; k < NPAIR; ++k) {
        float s = acc[k];
#pragma unroll
        for (int o = 32; o > 0; o >>= 1) s += __shfl_down(s, o, 64);
        if (lane == 0) lds[wid][k] = s;
    }
    __syncthreads();
    if (threadIdx.x < NPAIR) {
        e_s[threadIdx.x] = lds[0][threadIdx.x] + lds[1][threadIdx.x]
                         + lds[2][threadIdx.x] + lds[3][threadIdx.x];
    }
    __syncthreads();

    if (threadIdx.x < NN) {
        const int n = threadIdx.x;
        float z[NN];
#pragma unroll
        for (int m = 0; m < NN; ++m) {
            const int i = n < m ? n : m;
            const int j = n < m ? m : n;
            z[m] = -e_s[pair_idx(i, j)];
        }
        float mx = z[0];
#pragma unroll
        for (int m = 1; m < NN; ++m) mx = fmaxf(mx, z[m]);
        float p[NN], s = 0.f;
#pragma unroll
        for (int m = 0; m < NN; ++m) { p[m] = expf(z[m] - mx); s += p[m]; }
        const float inv = 1.f / s;
#pragma unroll
        for (int m = 0; m < NN; ++m)
            att[(size_t)b * NN * NN + n * NN + m] = p[m] * inv;
    }
}

// ---------------------------------------------------------------------------
// Kernel 3: LDS-staged apply with PIPELINED phase 2.
//   Phase 1: burst the 7 x2 sub-streams into LDS (R7, unchanged).
//   Phase 2 CHANGE: issue ALL 7 x1 loads upfront (7 outstanding 1KB
//   loads/wave instead of 1), then compute+store as each arrives.
//   Previous versions serialized load->wait->compute->store per n,
//   capping bytes-in-flight and the x1 stream at ~3.45 TB/s.
// ---------------------------------------------------------------------------
__global__ __launch_bounds__(THREADS)
void apply_k(const float* __restrict__ x1, const float* __restrict__ x2,
             const float* __restrict__ att, const float* __restrict__ gamma,
             float* __restrict__ out) {
    const int b     = blockIdx.x / ACPB;
    const int chunk = blockIdx.x % ACPB;
    const int p0    = chunk * ACH;

    __shared__ float4 x2s[NN * ACH];     // 28 KB
    __shared__ float  a_s[NN * NN];

    if (threadIdx.x < NN * NN)
        a_s[threadIdx.x] = att[(size_t)b * NN * NN + threadIdx.x];

    const float4* v2 = (const float4*)(x2 + (size_t)b * NN * D_EL);
#pragma unroll
    for (int m = 0; m < NN; ++m)
        x2s[m * ACH + threadIdx.x] = v2[(size_t)m * DV + p0 + threadIdx.x];
    __syncthreads();

    float4 v[NN];
#pragma unroll
    for (int m = 0; m < NN; ++m) v[m] = x2s[m * ACH + threadIdx.x];

    const float g = gamma[0];
    const float4* v1 = (const float4*)(x1 + (size_t)b * NN * D_EL);
    float4*       vo = (float4*)((float*)out + (size_t)b * NN * D_EL);
    const int p = p0 + threadIdx.x;

    // all 7 x1 loads in flight before any compute
    float4 x[NN];
#pragma unroll
    for (int n = 0; n < NN; ++n) x[n] = v1[(size_t)n * DV + p];

#pragma unroll
    for (int n = 0; n < NN; ++n) {
        float ox = 0.f, oy = 0.f, oz = 0.f, ow = 0.f;
#pragma unroll
        for (int m = 0; m < NN; ++m) {
            const float a = a_s[n * NN + m];
            ox = fmaf(a, v[m].x, ox);
            oy = fmaf(a, v[m].y, oy);
            oz = fmaf(a, v[m].z, oz);
            ow = fmaf(a, v[m].w, ow);
        }
        float4 r;
        r.x = fmaf(x[n].x, g * ox, x[n].x);
        r.y = fmaf(x[n].y, g * oy, x[n].y);
        r.z = fmaf(x[n].z, g * oz, x[n].z);
        r.w = fmaf(x[n].w, g * ow, x[n].w);
        vo[(size_t)n * DV + p] = r;
    }
}

extern "C" void kernel_launch(void* const* d_in, const int* in_sizes, int n_in,
                              void* d_out, int out_size, void* d_ws, size_t ws_size,
                              hipStream_t stream) {
    const float* x1    = (const float*)d_in[0];
    const float* x2    = (const float*)d_in[1];
    const float* gamma = (const float*)d_in[2];
    float*       out   = (float*)d_out;

    float* partials = (float*)d_ws;                         // NB*BPB*NPAIR floats
    float* att      = partials + (size_t)NB * BPB * NPAIR;  // NB*49 floats

    gram_partial<<<dim3(NB * BPB),  dim3(THREADS), 0, stream>>>(x2, partials);
    softmax_k  <<<dim3(NB),         dim3(THREADS), 0, stream>>>(partials, att);
    apply_k    <<<dim3(NB * ACPB),  dim3(THREADS), 0, stream>>>(x1, x2, att, gamma, out);
}